// Round 7
// baseline (203.907 us; speedup 1.0000x reference)
//
#include <hip/hip_runtime.h>
#include <hip/hip_bf16.h>

#define LN_EPS 1e-5f

typedef __attribute__((ext_vector_type(8))) short s8v;
typedef __attribute__((ext_vector_type(4))) float f32x4;

// ---------- helpers ----------
__device__ __forceinline__ float wred_sum(float v) {
#pragma unroll
  for (int o = 32; o > 0; o >>= 1) v += __shfl_xor(v, o, 64);
  return v;
}
__device__ __forceinline__ float bf2f(unsigned short u) {
  union { unsigned int i; float f; } c;
  c.i = ((unsigned int)u) << 16;
  return c.f;
}
__device__ __forceinline__ unsigned short f2bf(float f) {
  __hip_bfloat16 h = (__hip_bfloat16)f;
  return *(unsigned short*)&h;
}
__device__ __forceinline__ float4 bf4(ushort4 u) {
  return (float4){bf2f(u.x), bf2f(u.y), bf2f(u.z), bf2f(u.w)};
}
__device__ __forceinline__ void async_cp16(const __hip_bfloat16* g, __hip_bfloat16* l) {
  __builtin_amdgcn_global_load_lds(
      (const __attribute__((address_space(1))) unsigned int*)g,
      (__attribute__((address_space(3))) unsigned int*)l, 16, 0, 0);
}

// ---------- workspace layout (float units, 16B aligned) ----------
#define O_E     ((size_t)0)         // bf16 16384*256 -> 2097152 fl
#define O_P0B   ((size_t)2097152)   // bf16 4096*256  -> 524288 fl
#define O_W1T   ((size_t)2621440)   // bf16 1024*256  -> 131072 fl
#define O_HB    ((size_t)2752512)   // bf16 4096*1024 -> 2097152 fl
#define O_CTX   ((size_t)4849664)   // f32 6144   (zero block start)
#define O_XACC  ((size_t)4855808)   // f32 1024
#define O_PLAST ((size_t)4856832)   // f32 256
#define O_SSUM  ((size_t)4857088)   // f32 384 (6 layers x 64 spread slots)
#define O_KV    ((size_t)4857472)   // f32 1536
#define O_W2KV  ((size_t)4859008)   // f32 6144
#define O_SC    ((size_t)4865152)   // f32 24576 (holds exp(s) now)
#define N_ZERO  7808                // ctx+xacc+plast+ssum contiguous

// ---------- fused prep: ln(wpe)->p0b, ln(wte[tokens])->e, W1^T, zero accs ----
__global__ void prep_k(const float* __restrict__ wpe, const float* __restrict__ wte,
                       const int* __restrict__ tokens,
                       const float* __restrict__ g_p, const float* __restrict__ g_e,
                       const float* __restrict__ ff_w1,
                       unsigned short* __restrict__ p0b, unsigned short* __restrict__ e,
                       unsigned short* __restrict__ w1T, float* __restrict__ zeros) {
  __shared__ float lds[64][65];
  int bx = blockIdx.x, t = threadIdx.x;
  int w = t >> 6, lane = t & 63;

  if (bx < 5120) {  // layernorm roles, wave per row
    int row;
    const float* g;
    const float4* src;
    if (bx < 1024) {           // p0 = LN(wpe[:4096], g_p)
      row = bx * 4 + w;
      src = (const float4*)(wpe + (size_t)row * 256);
      g = g_p;
    } else {                   // e = LN(wte[tokens], g_e)
      row = (bx - 1024) * 4 + w;
      int tok = tokens[row];
      src = (const float4*)(wte + (size_t)tok * 256);
      g = g_e;
    }
    float4 v = src[lane];
    float mean = wred_sum(v.x + v.y + v.z + v.w) * (1.f / 256.f);
    float4 d = {v.x - mean, v.y - mean, v.z - mean, v.w - mean};
    float var = wred_sum(d.x * d.x + d.y * d.y + d.z * d.z + d.w * d.w) * (1.f / 256.f);
    float r = rsqrtf(var + LN_EPS);
    float4 gv = ((const float4*)g)[lane];
    ushort4 ob = {f2bf(d.x * r * gv.x), f2bf(d.y * r * gv.y),
                  f2bf(d.z * r * gv.z), f2bf(d.w * r * gv.w)};
    if (bx < 1024) ((ushort4*)(p0b + (size_t)row * 256))[lane] = ob;
    else           ((ushort4*)(e   + (size_t)row * 256))[lane] = ob;
    return;
  }
  if (bx < 5184) {  // transpose-cast W1 (256x1024) -> w1T (1024x256)
    int i = bx - 5120;
    int bxx = i & 3, byy = i >> 2;   // 4 x 16 tiles of 64x64
    int x = t & 63, y4 = t >> 6;
    int r0 = bxx * 64, c0 = byy * 64;
#pragma unroll
    for (int k = 0; k < 16; ++k) {
      int r = y4 * 16 + k;
      lds[r][x] = ff_w1[(size_t)(r0 + r) * 1024 + c0 + x];
    }
    __syncthreads();
#pragma unroll
    for (int k = 0; k < 16; ++k) {
      int a = y4 * 16 + k;
      w1T[(size_t)(c0 + a) * 256 + r0 + x] = f2bf(lds[x][a]);
    }
    return;
  }
  // bx == 5184: zero accumulators (ctx + xacc + plast + ssum)
  for (int i = t; i < N_ZERO; i += 256) zeros[i] = 0.f;
}

// ---------- MFMA GEMM: h = gelu(p0b @ W1^T), 64x64 tile, BK=64 --------------
// Fused plast epilogue: blocks with mtx==63 own row 4095; they stash the
// gelu'd h[4095] slice in LDS and do the split-k W2 dot -> atomicAdd(plast).
__global__ __launch_bounds__(256, 4) void mfma_gemm_mlp(
    const __hip_bfloat16* __restrict__ A, const __hip_bfloat16* __restrict__ BT,
    __hip_bfloat16* __restrict__ Cout,
    const float* __restrict__ W2, const unsigned short* __restrict__ p0b,
    float* __restrict__ plast) {
  __shared__ __hip_bfloat16 As[64 * 64];
  __shared__ __hip_bfloat16 Bs[64 * 64];
  __shared__ float hl[64];
  const int t = threadIdx.x;
  const int lane = t & 63, wave = t >> 6;
  const int wr = wave >> 1, wc = wave & 1;
  const int fr = lane & 15, quad = lane >> 4;
  const int mtx = blockIdx.x, ntx = blockIdx.y;
  const int m0 = mtx * 64, n0 = ntx * 64;

  f32x4 acc[2][2];
#pragma unroll
  for (int i = 0; i < 2; ++i)
#pragma unroll
    for (int j = 0; j < 2; ++j) acc[i][j] = (f32x4){0.f, 0.f, 0.f, 0.f};

  for (int k0 = 0; k0 < 256; k0 += 64) {
    __syncthreads();
#pragma unroll
    for (int j = 0; j < 2; ++j) {
      int ld = wave * 2 + j;
      int slot = ld * 64 + lane;
      int m = slot >> 3, c = slot & 7;
      async_cp16(A + (size_t)(m0 + m) * 256 + k0 + ((c ^ (m & 7)) << 3), As + ld * 512);
    }
#pragma unroll
    for (int j = 0; j < 2; ++j) {
      int ld = wave * 2 + j;
      int slot = ld * 64 + lane;
      int n = slot >> 3, c = slot & 7;
      async_cp16(BT + (size_t)(n0 + n) * 256 + k0 + ((c ^ (n & 7)) << 3), Bs + ld * 512);
    }
    __syncthreads();
#pragma unroll
    for (int h = 0; h < 2; ++h) {
      s8v af[2], bfv[2];
#pragma unroll
      for (int i = 0; i < 2; ++i) {
        int m = wr * 32 + i * 16 + fr;
        int ch = (h * 4 + quad) ^ (m & 7);
        af[i] = *(const s8v*)(As + m * 64 + ch * 8);
      }
#pragma unroll
      for (int j = 0; j < 2; ++j) {
        int n = wc * 32 + j * 16 + fr;
        int ch = (h * 4 + quad) ^ (n & 7);
        bfv[j] = *(const s8v*)(Bs + n * 64 + ch * 8);
      }
#pragma unroll
      for (int i = 0; i < 2; ++i)
#pragma unroll
        for (int j = 0; j < 2; ++j)
          acc[i][j] = __builtin_amdgcn_mfma_f32_16x16x32_bf16(af[i], bfv[j], acc[i][j], 0, 0, 0);
    }
  }

  // epilogue: exact gelu, store, stash row-4095 values for plast
#pragma unroll
  for (int i = 0; i < 2; ++i) {
#pragma unroll
    for (int j = 0; j < 2; ++j) {
#pragma unroll
      for (int r = 0; r < 4; ++r) {
        int row = m0 + wr * 32 + i * 16 + quad * 4 + r;
        int col = n0 + wc * 32 + j * 16 + fr;
        float v = acc[i][j][r];
        v = 0.5f * v * (1.f + erff(v * 0.70710678118654752f));
        Cout[(size_t)row * 1024 + col] = (__hip_bfloat16)v;
        if (mtx == 63 && row == 4095) hl[col - n0] = v;
      }
    }
  }
  // plast[t] = p0b[4095][t] + sum_k h[4095][k]*W2[k][t] (split-k over 16 blocks)
  if (mtx == 63) {
    __syncthreads();
    float pa = (ntx == 0) ? bf2f(p0b[(size_t)4095 * 256 + t]) : 0.f;
#pragma unroll
    for (int kk = 0; kk < 64; ++kk)
      pa += hl[kk] * W2[(size_t)(n0 + kk) * 256 + t];
    atomicAdd(&plast[t], pa);
  }
}

// ---------- fused q+kv+w2kv: grid (64,6) -------------------------------------
// Each block redundantly computes q[l]=plast@Wq[l] and kv[l]=Wk[l]@q[l] in LDS
// (intra-block __syncthreads only), then emits its 16 rows of w2kv[l]=W2@kv[l].
// Block bx==0 also writes kv[l] for sc_k. Redundant Wq/Wk reads are L2-shared.
__global__ __launch_bounds__(256) void qkw_k(
    const float* __restrict__ plast, const float* __restrict__ Wq,
    const float* __restrict__ Wk, const float* __restrict__ W2,
    float* __restrict__ kvout, float* __restrict__ w2kv) {
  __shared__ float spl[256];
  __shared__ float sq[256];
  __shared__ float skv[256];
  const int bx = blockIdx.x, l = blockIdx.y, t = threadIdx.x;
  const int w = t >> 6, lane = t & 63;

  spl[t] = plast[t];
  __syncthreads();
  // q[t] = sum_d plast[d] * Wq[l][d][t]   (coalesced over t)
  const float* Q = Wq + (size_t)l * 65536;
  float qa = 0.f;
#pragma unroll 8
  for (int d = 0; d < 256; ++d) qa += spl[d] * Q[(size_t)d * 256 + t];
  sq[t] = qa;
  __syncthreads();
  // kv[r] = Wk[l][r] . q   (wave per row, 64 rows/wave)
  const float* K = Wk + (size_t)l * 65536;
  float4 qv = ((const float4*)sq)[lane];
  for (int r = w; r < 256; r += 4) {
    float4 wv = ((const float4*)(K + (size_t)r * 256))[lane];
    float dot = wred_sum(wv.x * qv.x + wv.y * qv.y + wv.z * qv.z + wv.w * qv.w);
    if (lane == 0) skv[r] = dot;
  }
  __syncthreads();
  if (bx == 0) kvout[l * 256 + t] = skv[t];
  // w2kv rows r0..r0+15 (4 waves x 4 rows)
  const int r0 = bx * 16;
  float4 kf = ((const float4*)skv)[lane];
#pragma unroll
  for (int rr = 0; rr < 4; ++rr) {
    int r = r0 + w * 4 + rr;
    float4 wv = ((const float4*)(W2 + (size_t)r * 256))[lane];
    float dot = wred_sum(wv.x * kf.x + wv.y * kf.y + wv.z * kf.z + wv.w * kf.w);
    if (lane == 0) w2kv[l * 1024 + r] = dot;
  }
}

// ---------- sc_k: es[l][t] = exp((p0b[t].kv[l] + h[t].w2kv[l])/16) -----------
// No max-subtraction (|s| ~ 0.2 by construction). Per-block partial sums go to
// 64 spread slots per layer (8 atomics/slot) -> no hot-line serialization.
__global__ __launch_bounds__(256) void sc_k(
    const unsigned short* __restrict__ p0b, const unsigned short* __restrict__ hB,
    const float* __restrict__ kv, const float* __restrict__ w2kv,
    float* __restrict__ es, float* __restrict__ ssum) {
  __shared__ float skv[6 * 256];
  __shared__ float sw2[6 * 1024];
  __shared__ float sred[4][6];
  int t = threadIdx.x;
  for (int i = t; i < 1536; i += 256) skv[i] = kv[i];
  for (int i = t; i < 6144; i += 256) sw2[i] = w2kv[i];
  __syncthreads();
  int wave = t >> 6, lane = t & 63;
  float ps[6] = {0.f, 0.f, 0.f, 0.f, 0.f, 0.f};
#pragma unroll
  for (int rr = 0; rr < 2; ++rr) {
    int row = blockIdx.x * 8 + wave * 2 + rr;
    const ushort4* hrow = (const ushort4*)(hB + (size_t)row * 1024);
    float4 h0 = bf4(hrow[lane]);
    float4 h1 = bf4(hrow[64 + lane]);
    float4 h2 = bf4(hrow[128 + lane]);
    float4 h3 = bf4(hrow[192 + lane]);
    float4 p = bf4(((const ushort4*)(p0b + (size_t)row * 256))[lane]);
#pragma unroll
    for (int l = 0; l < 6; ++l) {
      float4 kf = ((const float4*)(skv + l * 256))[lane];
      float4 w0 = ((const float4*)(sw2 + l * 1024))[lane];
      float4 w1 = ((const float4*)(sw2 + l * 1024 + 256))[lane];
      float4 w2 = ((const float4*)(sw2 + l * 1024 + 512))[lane];
      float4 w3 = ((const float4*)(sw2 + l * 1024 + 768))[lane];
      float a = p.x * kf.x + p.y * kf.y + p.z * kf.z + p.w * kf.w;
      a += h0.x * w0.x + h0.y * w0.y + h0.z * w0.z + h0.w * w0.w;
      a += h1.x * w1.x + h1.y * w1.y + h1.z * w1.z + h1.w * w1.w;
      a += h2.x * w2.x + h2.y * w2.y + h2.z * w2.z + h2.w * w2.w;
      a += h3.x * w3.x + h3.y * w3.y + h3.z * w3.z + h3.w * w3.w;
      a = wred_sum(a) * 0.0625f;  // all lanes hold the total
      float ez = expf(a);
      ps[l] += ez;
      if (lane == 0) es[(size_t)l * 4096 + row] = ez;
    }
  }
  if (lane == 0) {
#pragma unroll
    for (int l = 0; l < 6; ++l) sred[wave][l] = ps[l];
  }
  __syncthreads();
  if (t < 6) {
    float s = sred[0][t] + sred[1][t] + sred[2][t] + sred[3][t];
    atomicAdd(&ssum[t * 64 + (blockIdx.x & 63)], s);
  }
}

// ---------- ctx: all 6 layers per block, 32 rows/chunk; scales by 1/sum ------
__global__ void ctx_k(const unsigned short* __restrict__ e, const float* __restrict__ es,
                      const float* __restrict__ ssum, float* __restrict__ ctx) {
  __shared__ float sld[384];
  __shared__ float sinv[6];
  int c = blockIdx.x, b = blockIdx.y, t = threadIdx.x;
  for (int i = t; i < 384; i += 256) sld[i] = ssum[i];  // FIX: strided (384>256)
  __syncthreads();
  if (t < 6) {
    float s = 0.f;
#pragma unroll
    for (int i = 0; i < 64; ++i) s += sld[t * 64 + i];
    sinv[t] = 1.f / s;
  }
  __syncthreads();
  const unsigned short* eb = e + ((size_t)b * 4096 + c * 32) * 256;
  const float* w0 = es + c * 32;
  float a[6] = {0.f, 0.f, 0.f, 0.f, 0.f, 0.f};
#pragma unroll 4
  for (int i = 0; i < 32; ++i) {
    float ev = bf2f(eb[(size_t)i * 256 + t]);
#pragma unroll
    for (int l = 0; l < 6; ++l) a[l] += w0[l * 4096 + i] * ev;
  }
#pragma unroll
  for (int l = 0; l < 6; ++l) atomicAdd(&ctx[(l * 4 + b) * 256 + t], a[l] * sinv[l]);
}

// ---------- xacc[b][t] += sum_l sum_{d in chunk} ctx[l][b][d]*Wv[l][d][t] ----
__global__ void proj_k(const float* __restrict__ ctx, const float* __restrict__ Wv,
                       float* __restrict__ xacc) {
  int c = blockIdx.x, l = blockIdx.y, t = threadIdx.x;
  const float* W = Wv + (size_t)l * 65536;
  float pa[4] = {0.f, 0.f, 0.f, 0.f};
#pragma unroll
  for (int i = 0; i < 16; ++i) {
    int d = c * 16 + i;
    float wv = W[d * 256 + t];  // coalesced
#pragma unroll
    for (int b = 0; b < 4; ++b) pa[b] += ctx[(l * 4 + b) * 256 + d] * wv;
  }
#pragma unroll
  for (int b = 0; b < 4; ++b) atomicAdd(&xacc[b * 256 + t], pa[b]);
}

// ---------- logits with fused final residual+LN (in-register per wave) ------
__global__ void logits_fin_k(const float* __restrict__ wte, const float* __restrict__ ge,
                             const float* __restrict__ gout,
                             const unsigned short* __restrict__ e,
                             const unsigned short* __restrict__ p0b,
                             const float* __restrict__ xacc,
                             float* __restrict__ out) {
  int wv = threadIdx.x >> 6, lane = threadIdx.x & 63;
  float4 go4 = ((const float4*)gout)[lane];
  float4 ge4 = ((const float4*)ge)[lane];
  float4 pl = bf4(((const ushort4*)(p0b + (size_t)4095 * 256))[lane]);
  float4 xb[4];
#pragma unroll
  for (int b = 0; b < 4; ++b) {
    float4 xa = ((const float4*)(xacc + b * 256))[lane];
    float4 ev = bf4(((const ushort4*)(e + ((size_t)(b * 4096 + 4095)) * 256))[lane]);
    float4 vv = {xa.x + ev.x + pl.x, xa.y + ev.y + pl.y,
                 xa.z + ev.z + pl.z, xa.w + ev.w + pl.w};
    float mean = wred_sum(vv.x + vv.y + vv.z + vv.w) * (1.f / 256.f);
    float4 d = {vv.x - mean, vv.y - mean, vv.z - mean, vv.w - mean};
    float var = wred_sum(d.x * d.x + d.y * d.y + d.z * d.z + d.w * d.w) * (1.f / 256.f);
    float r = rsqrtf(var + LN_EPS);
    xb[b] = (float4){d.x * r * go4.x, d.y * r * go4.y, d.z * r * go4.z, d.w * r * go4.w};
  }
  int v = blockIdx.x * 4 + wv;
  float4 x = ((const float4*)(wte + (size_t)v * 256))[lane];
  float mean = wred_sum(x.x + x.y + x.z + x.w) * (1.f / 256.f);
  float4 d = {x.x - mean, x.y - mean, x.z - mean, x.w - mean};
  float var = wred_sum(d.x * d.x + d.y * d.y + d.z * d.z + d.w * d.w) * (1.f / 256.f);
  float r = rsqrtf(var + LN_EPS);
  float4 ln = {d.x * r * ge4.x, d.y * r * ge4.y, d.z * r * ge4.z, d.w * r * ge4.w};
#pragma unroll
  for (int b = 0; b < 4; ++b) {
    float dot = wred_sum(ln.x * xb[b].x + ln.y * xb[b].y +
                         ln.z * xb[b].z + ln.w * xb[b].w);
    if (lane == 0) out[b * 32000 + v] = dot;
  }
}

extern "C" void kernel_launch(void* const* d_in, const int* in_sizes, int n_in,
                              void* d_out, int out_size, void* d_ws, size_t ws_size,
                              hipStream_t stream) {
  const int*   tokens = (const int*)d_in[0];
  const float* wte    = (const float*)d_in[1];
  const float* wpe    = (const float*)d_in[2];
  const float* g_e    = (const float*)d_in[3];
  const float* g_p    = (const float*)d_in[4];
  const float* g_out  = (const float*)d_in[5];
  const float* ff_w1  = (const float*)d_in[6];
  const float* ff_w2  = (const float*)d_in[7];
  const float* Wq     = (const float*)d_in[8];
  const float* Wk     = (const float*)d_in[9];
  const float* Wv     = (const float*)d_in[10];
  float* out = (float*)d_out;
  float* ws = (float*)d_ws;

  unsigned short* e   = (unsigned short*)(ws + O_E);
  unsigned short* p0b = (unsigned short*)(ws + O_P0B);
  unsigned short* w1T = (unsigned short*)(ws + O_W1T);
  unsigned short* hB  = (unsigned short*)(ws + O_HB);
  float* ctx   = ws + O_CTX;
  float* xacc  = ws + O_XACC;
  float* plast = ws + O_PLAST;
  float* ssum  = ws + O_SSUM;
  float* kv    = ws + O_KV;
  float* w2kv  = ws + O_W2KV;
  float* esbuf = ws + O_SC;

  // 1. fused prep (LNs -> bf16, W1^T, zero ctx/xacc/plast/ssum)
  prep_k<<<5185, 256, 0, stream>>>(wpe, wte, tokens, g_p, g_e, ff_w1,
                                   p0b, e, w1T, ctx);
  // 2. MLP1: h = gelu(p0 @ W1) with fused plast epilogue
  mfma_gemm_mlp<<<dim3(64, 16), 256, 0, stream>>>(
      (const __hip_bfloat16*)p0b, (const __hip_bfloat16*)w1T,
      (__hip_bfloat16*)hB, ff_w2, p0b, plast);
  // 3. fused q+kv+w2kv (redundant per-block recompute, intra-block sync only)
  qkw_k<<<dim3(64, 6), 256, 0, stream>>>(plast, Wq, Wk, ff_w2, kv, w2kv);
  // 4. scores -> exp(s) + spread partial sums (softmax kernel eliminated)
  sc_k<<<512, 256, 0, stream>>>(p0b, hB, kv, w2kv, esbuf, ssum);
  // 5. ctx accumulation (scales by 1/sum per layer)
  ctx_k<<<dim3(128, 4), 256, 0, stream>>>(e, esbuf, ssum, ctx);
  // 6. Wv projection (split-d atomics into xacc)
  proj_k<<<dim3(16, 6), 256, 0, stream>>>(ctx, Wv, xacc);
  // 7. logits with fused final residual+LN
  logits_fin_k<<<8000, 256, 0, stream>>>(wte, g_e, g_out, e, p0b, xacc, out);
}